// Round 1
// baseline (119.166 us; speedup 1.0000x reference)
//
#include <hip/hip_runtime.h>
#include <stdint.h>

#define TSTEPS 6
#define BB 512
#define SS 40
#define VV 28
#define NPK 512
#define NION 111

#define PROTON 1.007276f
#define WATER 18.010565f
#define CO 27.994915f

// ---------------- block reduction helper ----------------
__device__ __forceinline__ float blockReduceSum(float v, float* lds) {
#pragma unroll
  for (int off = 32; off > 0; off >>= 1) v += __shfl_down(v, off);
  int lane = threadIdx.x & 63, wid = threadIdx.x >> 6;
  if (lane == 0) lds[wid] = v;
  __syncthreads();
  int nw = (blockDim.x + 63) >> 6;
  v = (threadIdx.x < nw) ? lds[threadIdx.x] : 0.0f;
  if (wid == 0) {
#pragma unroll
    for (int off = 32; off > 0; off >>= 1) v += __shfl_down(v, off);
  }
  return v;  // valid in thread 0
}

// ---------------- init + bool-dtype detection ----------------
// If masks are stored as 4-byte words (int32/float32 0/1), bytes at i%4==1 are
// all zero. If stored as 1-byte numpy bool (~80% true), many are nonzero.
__global__ void k_init(const uint8_t* __restrict__ mask_bytes, float* acc, int* flag) {
  if (threadIdx.x == 0 && blockIdx.x == 0) {
    int f = 0;
    for (int i = 1; i < 4096; i += 4) f |= (mask_bytes[i] != 0) ? 1 : 0;
    *flag = f;  // 1 => 1-byte bools, 0 => 4-byte words (nonzero == true)
    acc[0] = 0.0f; acc[1] = 0.0f; acc[2] = 0.0f; acc[3] = 0.0f;
  }
}

// ---------------- deep supervision CE ----------------
// acc[0] += sum_t,b,s w_t * ce * mf ; acc[1] += sum_b,s mf
__global__ void k_ce(const float* __restrict__ logits,
                     const int* __restrict__ targets,
                     const uint8_t* __restrict__ mask8,
                     float* acc, const int* __restrict__ flag) {
  __shared__ float lds[16];
  int tid = blockIdx.x * blockDim.x + threadIdx.x;
  float ce_c = 0.0f, mf_c = 0.0f;
  const int fl = *flag;
  if (tid < TSTEPS * BB * SS) {
    int t = tid / (BB * SS);
    int bs = tid - t * (BB * SS);
    const float* row = logits + (size_t)tid * VV;
    const float4* r4 = (const float4*)row;
    float4 q0 = r4[0], q1 = r4[1], q2 = r4[2], q3 = r4[3], q4 = r4[4], q5 = r4[5], q6 = r4[6];
    float m = q0.x;
    m = fmaxf(m, q0.y); m = fmaxf(m, q0.z); m = fmaxf(m, q0.w);
    m = fmaxf(m, q1.x); m = fmaxf(m, q1.y); m = fmaxf(m, q1.z); m = fmaxf(m, q1.w);
    m = fmaxf(m, q2.x); m = fmaxf(m, q2.y); m = fmaxf(m, q2.z); m = fmaxf(m, q2.w);
    m = fmaxf(m, q3.x); m = fmaxf(m, q3.y); m = fmaxf(m, q3.z); m = fmaxf(m, q3.w);
    m = fmaxf(m, q4.x); m = fmaxf(m, q4.y); m = fmaxf(m, q4.z); m = fmaxf(m, q4.w);
    m = fmaxf(m, q5.x); m = fmaxf(m, q5.y); m = fmaxf(m, q5.z); m = fmaxf(m, q5.w);
    m = fmaxf(m, q6.x); m = fmaxf(m, q6.y); m = fmaxf(m, q6.z); m = fmaxf(m, q6.w);
    float se = 0.0f;
    se += __expf(q0.x - m) + __expf(q0.y - m) + __expf(q0.z - m) + __expf(q0.w - m);
    se += __expf(q1.x - m) + __expf(q1.y - m) + __expf(q1.z - m) + __expf(q1.w - m);
    se += __expf(q2.x - m) + __expf(q2.y - m) + __expf(q2.z - m) + __expf(q2.w - m);
    se += __expf(q3.x - m) + __expf(q3.y - m) + __expf(q3.z - m) + __expf(q3.w - m);
    se += __expf(q4.x - m) + __expf(q4.y - m) + __expf(q4.z - m) + __expf(q4.w - m);
    se += __expf(q5.x - m) + __expf(q5.y - m) + __expf(q5.z - m) + __expf(q5.w - m);
    se += __expf(q6.x - m) + __expf(q6.y - m) + __expf(q6.z - m) + __expf(q6.w - m);
    float lse = m + __logf(se);
    int tgt = targets[bs];
    bool msk = fl ? (mask8[bs] != 0) : (((const uint32_t*)mask8)[bs] != 0u);
    float mf = msk ? 1.0f : 0.0f;
    if (tgt != 0) {
      float w = (float)(t + 1) * (1.0f / 21.0f);
      ce_c = w * (lse - row[tgt]) * mf;
    }
    if (t == 0) mf_c = mf;
  }
  float s1 = blockReduceSum(ce_c, lds);
  __syncthreads();
  float s2 = blockReduceSum(mf_c, lds);
  if (threadIdx.x == 0) {
    atomicAdd(&acc[0], s1);
    atomicAdd(&acc[1], s2);
  }
}

// ---------------- spectrum loss: one block per batch b ----------------
// acc[2] += sum matched*iw*nm ; acc[3] += sum nm
__global__ void __launch_bounds__(128) k_spec(
    const float* __restrict__ logits5,  // (B,S,V) final layer
    const float* __restrict__ obs_m,    // (B,NPK)
    const float* __restrict__ obs_i,    // (B,NPK)
    const uint8_t* __restrict__ pmask8, // (B,NPK) bool
    const float* __restrict__ aa,       // (V,)
    float* acc, const int* __restrict__ flag) {
  __shared__ float s_mass[NPK];
  __shared__ float s_int[NPK];
  __shared__ float s_exp[SS];
  __shared__ float s_theo[NION];
  __shared__ float s_aa[VV];
  __shared__ float lds[16];

  const int b = blockIdx.x;
  const int tid = threadIdx.x;
  const int fl = *flag;

  if (tid < VV) s_aa[tid] = aa[tid];

  // stage peaks; fold peak_mask into mass (1e30 never matches the 0.5 window)
  for (int p = tid; p < NPK; p += 128) {
    bool pm = fl ? (pmask8[(size_t)b * NPK + p] != 0)
                 : (((const uint32_t*)pmask8)[(size_t)b * NPK + p] != 0u);
    s_mass[p] = pm ? obs_m[(size_t)b * NPK + p] : 1e30f;
    s_int[p] = obs_i[(size_t)b * NPK + p];
  }
  __syncthreads();

  // expected mass per position: softmax(logits) . aa
  if (tid < SS) {
    const float* row = logits5 + ((size_t)b * SS + tid) * VV;
    float m = -1e30f;
#pragma unroll
    for (int v = 0; v < VV; v++) m = fmaxf(m, row[v]);
    float se = 0.0f, sw = 0.0f;
#pragma unroll
    for (int v = 0; v < VV; v++) {
      float e = __expf(row[v] - m);
      se += e;
      sw += e * s_aa[v];
    }
    s_exp[tid] = sw / se;
  }
  __syncthreads();

  // theoretical ions (serial 38-element scans; negligible)
  if (tid == 0) {
    float c = 0.0f;
#pragma unroll
    for (int j = 0; j < 37; j++) {
      c += s_exp[1 + j];                    // residue j = expected[1+j]
      s_theo[j] = c + PROTON;               // b ions
      s_theo[74 + j] = c + PROTON - CO;     // a ions
    }
    float c2 = 0.0f;
#pragma unroll
    for (int j = 37; j >= 0; j--) {
      c2 += s_exp[1 + j];                   // suffix sum from j
      if (j <= 36) s_theo[37 + j] = c2 + WATER + PROTON;  // y ions
    }
  }
  __syncthreads();

  float contrib = 0.0f, cnt = 0.0f;
  if (tid < NION) {
    const float th = s_theo[tid];
    // pass 1: min distance among (masked-folded) peaks
    float dmin = 1e30f;
    for (int p = 0; p < NPK; p++) dmin = fminf(dmin, fabsf(th - s_mass[p]));
    if (dmin < 0.5f) {
      // pass 2: online-softmax accumulate with known max score -dmin*10
      float se = 0.0f, sh = 0.0f, si = 0.0f;
      for (int p = 0; p < NPK; p++) {
        float d = fabsf(th - s_mass[p]);
        float e = __expf((dmin - d) * 10.0f);
        e = (d < 0.5f) ? e : 0.0f;
        float hub = (d <= 0.2f) ? (0.5f * d * d) : (0.2f * (d - 0.1f));
        se += e;
        sh += e * hub;
        si += e * s_int[p];
      }
      contrib = (sh / se) * (si / se);
      cnt = 1.0f;
    }
  }
  float s1 = blockReduceSum(contrib, lds);
  __syncthreads();
  float s2 = blockReduceSum(cnt, lds);
  if (tid == 0) {
    atomicAdd(&acc[2], s1);
    atomicAdd(&acc[3], s2);
  }
}

// ---------------- final combine ----------------
__global__ void k_final(const float* __restrict__ acc, float* __restrict__ out) {
  if (threadIdx.x == 0 && blockIdx.x == 0) {
    float denom = fmaxf(acc[1], 1.0f);
    float ce = acc[0] / denom;
    float nms = fmaxf(acc[3], 1.0f);
    float spec = acc[2] / nms;
    out[0] = ce + 0.1f * spec;
  }
}

extern "C" void kernel_launch(void* const* d_in, const int* in_sizes, int n_in,
                              void* d_out, int out_size, void* d_ws, size_t ws_size,
                              hipStream_t stream) {
  const float* all_logits = (const float*)d_in[0];
  const int* targets = (const int*)d_in[1];
  const uint8_t* target_mask = (const uint8_t*)d_in[2];
  const float* obs_m = (const float*)d_in[3];
  const float* obs_i = (const float*)d_in[4];
  const uint8_t* peak_mask = (const uint8_t*)d_in[5];
  const float* aa = (const float*)d_in[6];
  float* out = (float*)d_out;

  float* acc = (float*)d_ws;        // acc[0..3]
  int* flag = ((int*)d_ws) + 8;     // dtype flag

  k_init<<<1, 64, 0, stream>>>(target_mask, acc, flag);

  const int rows = TSTEPS * BB * SS;
  k_ce<<<(rows + 255) / 256, 256, 0, stream>>>(all_logits, targets, target_mask, acc, flag);

  const float* logits5 = all_logits + (size_t)5 * BB * SS * VV;
  k_spec<<<BB, 128, 0, stream>>>(logits5, obs_m, obs_i, peak_mask, aa, acc, flag);

  k_final<<<1, 64, 0, stream>>>(acc, out);
}

// Round 2
// 39.888 us; speedup vs baseline: 2.9876x; 2.9876x over previous
//
#include <hip/hip_runtime.h>
#include <stdint.h>

#define TSTEPS 6
#define BB 512
#define SS 40
#define VV 28
#define NPK 512
#define NION 111
#define NB_CE 480  // 480*256 = 122880 = T*B*S rows

#define PROTON 1.007276f
#define WATER 18.010565f
#define CO 27.994915f

// ---------------- block reduction helper ----------------
__device__ __forceinline__ float blockReduceSum(float v, float* red) {
#pragma unroll
  for (int off = 32; off > 0; off >>= 1) v += __shfl_down(v, off);
  int lane = threadIdx.x & 63, wid = threadIdx.x >> 6;
  if (lane == 0) red[wid] = v;
  __syncthreads();
  int nw = (blockDim.x + 63) >> 6;
  v = (threadIdx.x < nw) ? red[threadIdx.x] : 0.0f;
  if (wid == 0) {
#pragma unroll
    for (int off = 32; off > 0; off >>= 1) v += __shfl_down(v, off);
  }
  return v;  // valid in thread 0
}

// ---------------- bool-dtype detection (per block, parallel) ----------------
// If masks are 4-byte words (int32/fp32 0/1), bytes at i%4==1 are all zero.
// If 1-byte numpy bool (~70-80% true), many are nonzero. Scans first 4096 B.
__device__ __forceinline__ int detectBoolFlag(const uint8_t* __restrict__ bytes,
                                              int* s_fl) {
  if (threadIdx.x == 0) *s_fl = 0;
  __syncthreads();
  int f = 0;
  for (int k = threadIdx.x; k < 1024; k += 256) f |= (bytes[1 + 4 * k] != 0) ? 1 : 0;
  if (f) *s_fl = 1;  // benign race: all writers store 1
  __syncthreads();
  return *s_fl;
}

// ---------------- init: zero accumulators (ws is poisoned once) ----------------
__global__ void k_init(float* acc) {
  if (threadIdx.x < 4 && blockIdx.x == 0) acc[threadIdx.x] = 0.0f;
}

// ---------------- fused CE + spectrum ----------------
// blocks [0, NB_CE)        : deep-supervision CE   -> acc[0] (weighted ce), acc[1] (mask count)
// blocks [NB_CE, NB_CE+BB) : spectrum loss, b=blk-NB_CE -> acc[2] (sum), acc[3] (nm count)
__global__ void __launch_bounds__(256) k_fused(
    const float* __restrict__ logits,   // (T,B,S,V)
    const int* __restrict__ targets,    // (B,S)
    const uint8_t* __restrict__ tmask8, // (B,S) bool or int words
    const float* __restrict__ obs_m,    // (B,NPK) sorted
    const float* __restrict__ obs_i,    // (B,NPK)
    const uint8_t* __restrict__ pmask8, // (B,NPK)
    const float* __restrict__ aa,       // (V,)
    float* acc) {
  __shared__ float red[16];
  __shared__ int s_fl;
  const int tid = threadIdx.x;

  if (blockIdx.x < NB_CE) {
    // ================= CE path =================
    const int fl = detectBoolFlag(tmask8, &s_fl);
    const int row_id = blockIdx.x * 256 + tid;  // < T*B*S exactly
    const int t = row_id / (BB * SS);
    const int bs = row_id - t * (BB * SS);
    const float* row = logits + (size_t)row_id * VV;
    const float4* r4 = (const float4*)row;
    float4 q0 = r4[0], q1 = r4[1], q2 = r4[2], q3 = r4[3], q4 = r4[4], q5 = r4[5], q6 = r4[6];
    float m = q0.x;
    m = fmaxf(m, q0.y); m = fmaxf(m, q0.z); m = fmaxf(m, q0.w);
    m = fmaxf(m, q1.x); m = fmaxf(m, q1.y); m = fmaxf(m, q1.z); m = fmaxf(m, q1.w);
    m = fmaxf(m, q2.x); m = fmaxf(m, q2.y); m = fmaxf(m, q2.z); m = fmaxf(m, q2.w);
    m = fmaxf(m, q3.x); m = fmaxf(m, q3.y); m = fmaxf(m, q3.z); m = fmaxf(m, q3.w);
    m = fmaxf(m, q4.x); m = fmaxf(m, q4.y); m = fmaxf(m, q4.z); m = fmaxf(m, q4.w);
    m = fmaxf(m, q5.x); m = fmaxf(m, q5.y); m = fmaxf(m, q5.z); m = fmaxf(m, q5.w);
    m = fmaxf(m, q6.x); m = fmaxf(m, q6.y); m = fmaxf(m, q6.z); m = fmaxf(m, q6.w);
    float se = 0.0f;
    se += __expf(q0.x - m) + __expf(q0.y - m) + __expf(q0.z - m) + __expf(q0.w - m);
    se += __expf(q1.x - m) + __expf(q1.y - m) + __expf(q1.z - m) + __expf(q1.w - m);
    se += __expf(q2.x - m) + __expf(q2.y - m) + __expf(q2.z - m) + __expf(q2.w - m);
    se += __expf(q3.x - m) + __expf(q3.y - m) + __expf(q3.z - m) + __expf(q3.w - m);
    se += __expf(q4.x - m) + __expf(q4.y - m) + __expf(q4.z - m) + __expf(q4.w - m);
    se += __expf(q5.x - m) + __expf(q5.y - m) + __expf(q5.z - m) + __expf(q5.w - m);
    se += __expf(q6.x - m) + __expf(q6.y - m) + __expf(q6.z - m) + __expf(q6.w - m);
    float lse = m + __logf(se);
    int tgt = targets[bs];
    bool msk = fl ? (tmask8[bs] != 0) : (((const uint32_t*)tmask8)[bs] != 0u);
    float mf = msk ? 1.0f : 0.0f;
    float ce_c = 0.0f, mf_c = 0.0f;
    if (tgt != 0) {
      float w = (float)(t + 1) * (1.0f / 21.0f);
      ce_c = w * (lse - row[tgt]) * mf;
    }
    if (t == 0) mf_c = mf;
    float s1 = blockReduceSum(ce_c, red);
    __syncthreads();
    float s2 = blockReduceSum(mf_c, red);
    if (tid == 0) {
      atomicAdd(&acc[0], s1);
      atomicAdd(&acc[1], s2);
    }
  } else {
    // ================= spectrum path =================
    __shared__ float s_mass[NPK];
    __shared__ float s_int[NPK];   // negative => masked-out peak
    __shared__ float s_exp[SS];
    __shared__ float s_theo[NION];
    __shared__ float s_aa[VV];
    const int b = blockIdx.x - NB_CE;
    const int fl = detectBoolFlag(pmask8, &s_fl);

    if (tid < VV) s_aa[tid] = aa[tid];
    for (int p = tid; p < NPK; p += 256) {
      bool pm = fl ? (pmask8[(size_t)b * NPK + p] != 0)
                   : (((const uint32_t*)pmask8)[(size_t)b * NPK + p] != 0u);
      s_mass[p] = obs_m[(size_t)b * NPK + p];  // keep sorted (true values)
      float iv = obs_i[(size_t)b * NPK + p];
      s_int[p] = pm ? iv : -1.0f;
    }
    __syncthreads();

    // expected mass per position: softmax(final logits) . aa
    if (tid < SS) {
      const float* row = logits + ((size_t)(TSTEPS - 1) * BB * SS + (size_t)b * SS + tid) * VV;
      float m = -1e30f;
#pragma unroll
      for (int v = 0; v < VV; v++) m = fmaxf(m, row[v]);
      float se = 0.0f, sw = 0.0f;
#pragma unroll
      for (int v = 0; v < VV; v++) {
        float e = __expf(row[v] - m);
        se += e;
        sw += e * s_aa[v];
      }
      s_exp[tid] = sw / se;
    }
    __syncthreads();

    // theoretical ions (38-element serial scans; negligible)
    if (tid == 0) {
      float c = 0.0f;
#pragma unroll
      for (int j = 0; j < 37; j++) {
        c += s_exp[1 + j];
        s_theo[j] = c + PROTON;             // b ions
        s_theo[74 + j] = c + PROTON - CO;   // a ions
      }
      float c2 = 0.0f;
#pragma unroll
      for (int j = 37; j >= 0; j--) {
        c2 += s_exp[1 + j];
        if (j <= 36) s_theo[37 + j] = c2 + WATER + PROTON;  // y ions
      }
    }
    __syncthreads();

    float contrib = 0.0f, cnt = 0.0f;
    if (tid < NION) {
      const float th = s_theo[tid];
      // binary search: first index with mass > th - 0.5
      const float lim = th - 0.5f;
      int lo = 0, hi = NPK;
      while (lo < hi) {
        int mid = (lo + hi) >> 1;
        if (s_mass[mid] <= lim) lo = mid + 1; else hi = mid;
      }
      // walk the (tiny) window; scores in [-5,0] => direct exp is stable
      float se = 0.0f, sh = 0.0f, si = 0.0f;
      int has = 0;
      for (int p = lo; p < NPK; ++p) {
        float ms = s_mass[p];
        if (!(ms < th + 0.5f)) break;
        float iv = s_int[p];
        if (iv < 0.0f) continue;  // masked peak
        float d = fabsf(th - ms);
        if (!(d < 0.5f)) continue;
        float e = __expf(-10.0f * d);
        float hub = (d <= 0.2f) ? (0.5f * d * d) : (0.2f * (d - 0.1f));
        se += e; sh += e * hub; si += e * iv;
        has = 1;
      }
      if (has) {
        contrib = (sh / se) * (si / se);
        cnt = 1.0f;
      }
    }
    float s1 = blockReduceSum(contrib, red);
    __syncthreads();
    float s2 = blockReduceSum(cnt, red);
    if (tid == 0) {
      atomicAdd(&acc[2], s1);
      atomicAdd(&acc[3], s2);
    }
  }
}

// ---------------- final combine ----------------
__global__ void k_final(const float* __restrict__ acc, float* __restrict__ out) {
  if (threadIdx.x == 0 && blockIdx.x == 0) {
    float denom = fmaxf(acc[1], 1.0f);
    float ce = acc[0] / denom;
    float nms = fmaxf(acc[3], 1.0f);
    float spec = acc[2] / nms;
    out[0] = ce + 0.1f * spec;
  }
}

extern "C" void kernel_launch(void* const* d_in, const int* in_sizes, int n_in,
                              void* d_out, int out_size, void* d_ws, size_t ws_size,
                              hipStream_t stream) {
  const float* all_logits = (const float*)d_in[0];
  const int* targets = (const int*)d_in[1];
  const uint8_t* target_mask = (const uint8_t*)d_in[2];
  const float* obs_m = (const float*)d_in[3];
  const float* obs_i = (const float*)d_in[4];
  const uint8_t* peak_mask = (const uint8_t*)d_in[5];
  const float* aa = (const float*)d_in[6];
  float* out = (float*)d_out;

  float* acc = (float*)d_ws;  // acc[0..3]

  k_init<<<1, 64, 0, stream>>>(acc);
  k_fused<<<NB_CE + BB, 256, 0, stream>>>(all_logits, targets, target_mask,
                                          obs_m, obs_i, peak_mask, aa, acc);
  k_final<<<1, 64, 0, stream>>>(acc, out);
}

// Round 3
// 16.684 us; speedup vs baseline: 7.1427x; 2.3908x over previous
//
#include <hip/hip_runtime.h>
#include <stdint.h>

#define TSTEPS 6
#define BB 512
#define SS 40
#define VV 28
#define NPK 512
#define NION 111
#define NB_CE 480             // 480*256 = 122880 = T*B*S rows
#define NBLK (NB_CE + BB)     // 992

#define PROTON 1.007276f
#define WATER 18.010565f
#define CO 27.994915f

// ---------------- block reduction helper ----------------
__device__ __forceinline__ float blockReduceSum(float v, float* red) {
#pragma unroll
  for (int off = 32; off > 0; off >>= 1) v += __shfl_down(v, off);
  int lane = threadIdx.x & 63, wid = threadIdx.x >> 6;
  if (lane == 0) red[wid] = v;
  __syncthreads();
  int nw = (blockDim.x + 63) >> 6;
  v = (threadIdx.x < nw) ? red[threadIdx.x] : 0.0f;
  if (wid == 0) {
#pragma unroll
    for (int off = 32; off > 0; off >>= 1) v += __shfl_down(v, off);
  }
  return v;  // valid in thread 0
}

// ---------------- bool-dtype detection (per block, parallel) ----------------
// 4-byte-word masks (int/fp 0/1) have all-zero bytes at i%4==1; 1-byte numpy
// bools (~70-80% true) don't. Scans first 4096 bytes (L2-broadcast, cheap).
__device__ __forceinline__ int detectBoolFlag(const uint8_t* __restrict__ bytes,
                                              int* s_fl) {
  if (threadIdx.x == 0) *s_fl = 0;
  __syncthreads();
  int f = 0;
  for (int k = threadIdx.x; k < 1024; k += 256) f |= (bytes[1 + 4 * k] != 0) ? 1 : 0;
  if (f) *s_fl = 1;  // benign race: all writers store 1
  __syncthreads();
  return *s_fl;
}

// ---------------- fused CE + spectrum ----------------
// blocks [0, NB_CE)        : deep-supervision CE -> partial[2i] = weighted ce, [2i+1] = mask count
// blocks [NB_CE, NBLK)     : spectrum, b = blk-NB_CE -> partial[2i] = sum, [2i+1] = nm count
__global__ void __launch_bounds__(256) k_fused(
    const float* __restrict__ logits,   // (T,B,S,V)
    const int* __restrict__ targets,    // (B,S)
    const uint8_t* __restrict__ tmask8, // (B,S)
    const float* __restrict__ obs_m,    // (B,NPK) sorted
    const float* __restrict__ obs_i,    // (B,NPK)
    const uint8_t* __restrict__ pmask8, // (B,NPK)
    const float* __restrict__ aa,       // (V,)
    float* __restrict__ partial) {
  __shared__ float s[7168];   // 28 KB staging, reused by both paths
  __shared__ float red[8];
  __shared__ int s_fl;
  const int tid = threadIdx.x;

  if (blockIdx.x < NB_CE) {
    // ================= CE path =================
    const int fl = detectBoolFlag(tmask8, &s_fl);
    // coalesced stage: 1792 float4 per block (256 rows x 112 B)
    const float4* g4 = (const float4*)logits + (size_t)blockIdx.x * 1792;
    float4* l4 = (float4*)s;
#pragma unroll
    for (int it = 0; it < 7; ++it) l4[it * 256 + tid] = g4[it * 256 + tid];
    __syncthreads();

    const int row_id = blockIdx.x * 256 + tid;
    const int t = row_id / (BB * SS);
    const int bs = row_id - t * (BB * SS);
    float4 q0 = l4[tid * 7 + 0], q1 = l4[tid * 7 + 1], q2 = l4[tid * 7 + 2],
           q3 = l4[tid * 7 + 3], q4 = l4[tid * 7 + 4], q5 = l4[tid * 7 + 5],
           q6 = l4[tid * 7 + 6];
    float m = q0.x;
    m = fmaxf(m, q0.y); m = fmaxf(m, q0.z); m = fmaxf(m, q0.w);
    m = fmaxf(m, q1.x); m = fmaxf(m, q1.y); m = fmaxf(m, q1.z); m = fmaxf(m, q1.w);
    m = fmaxf(m, q2.x); m = fmaxf(m, q2.y); m = fmaxf(m, q2.z); m = fmaxf(m, q2.w);
    m = fmaxf(m, q3.x); m = fmaxf(m, q3.y); m = fmaxf(m, q3.z); m = fmaxf(m, q3.w);
    m = fmaxf(m, q4.x); m = fmaxf(m, q4.y); m = fmaxf(m, q4.z); m = fmaxf(m, q4.w);
    m = fmaxf(m, q5.x); m = fmaxf(m, q5.y); m = fmaxf(m, q5.z); m = fmaxf(m, q5.w);
    m = fmaxf(m, q6.x); m = fmaxf(m, q6.y); m = fmaxf(m, q6.z); m = fmaxf(m, q6.w);
    float se = 0.0f;
    se += __expf(q0.x - m) + __expf(q0.y - m) + __expf(q0.z - m) + __expf(q0.w - m);
    se += __expf(q1.x - m) + __expf(q1.y - m) + __expf(q1.z - m) + __expf(q1.w - m);
    se += __expf(q2.x - m) + __expf(q2.y - m) + __expf(q2.z - m) + __expf(q2.w - m);
    se += __expf(q3.x - m) + __expf(q3.y - m) + __expf(q3.z - m) + __expf(q3.w - m);
    se += __expf(q4.x - m) + __expf(q4.y - m) + __expf(q4.z - m) + __expf(q4.w - m);
    se += __expf(q5.x - m) + __expf(q5.y - m) + __expf(q5.z - m) + __expf(q5.w - m);
    se += __expf(q6.x - m) + __expf(q6.y - m) + __expf(q6.z - m) + __expf(q6.w - m);
    float lse = m + __logf(se);
    int tgt = targets[bs];
    bool msk = fl ? (tmask8[bs] != 0) : (((const uint32_t*)tmask8)[bs] != 0u);
    float mf = msk ? 1.0f : 0.0f;
    float ce_c = 0.0f, mf_c = 0.0f;
    if (tgt != 0) {
      float w = (float)(t + 1) * (1.0f / 21.0f);
      ce_c = w * (lse - s[tid * VV + tgt]) * mf;
    }
    if (t == 0) mf_c = mf;
    float s1 = blockReduceSum(ce_c, red);
    __syncthreads();
    float s2 = blockReduceSum(mf_c, red);
    if (tid == 0) {
      partial[2 * blockIdx.x] = s1;
      partial[2 * blockIdx.x + 1] = s2;
    }
  } else {
    // ================= spectrum path =================
    float* s_mass = s;            // [0..511]
    float* s_int = s + 512;       // [512..1023]   negative => masked peak
    float* s_logit = s + 1024;    // [1024..2143]  40x28 final-layer rows
    float* s_exp = s + 2144;      // [2144..2183]
    float* s_theo = s + 2184;     // [2184..2294]
    float* s_aa = s + 2304;       // [2304..2331]
    const int b = blockIdx.x - NB_CE;
    const int fl = detectBoolFlag(pmask8, &s_fl);

    if (tid < VV) s_aa[tid] = aa[tid];
    for (int p = tid; p < NPK; p += 256) {
      bool pm = fl ? (pmask8[(size_t)b * NPK + p] != 0)
                   : (((const uint32_t*)pmask8)[(size_t)b * NPK + p] != 0u);
      s_mass[p] = obs_m[(size_t)b * NPK + p];  // keep sorted (true values)
      float iv = obs_i[(size_t)b * NPK + p];
      s_int[p] = pm ? iv : -1.0f;
    }
    // coalesced stage of this batch's final-layer logits: 280 float4
    {
      const float4* g4 = (const float4*)(logits +
          (size_t)(TSTEPS - 1) * BB * SS * VV + (size_t)b * SS * VV);
      float4* l4 = (float4*)s_logit;
      for (int it = tid; it < 280; it += 256) l4[it] = g4[it];
    }
    __syncthreads();

    // expected mass per position: softmax(final logits) . aa
    if (tid < SS) {
      const float* row = s_logit + tid * VV;
      float m = -1e30f;
#pragma unroll
      for (int v = 0; v < VV; v++) m = fmaxf(m, row[v]);
      float se = 0.0f, sw = 0.0f;
#pragma unroll
      for (int v = 0; v < VV; v++) {
        float e = __expf(row[v] - m);
        se += e;
        sw += e * s_aa[v];
      }
      s_exp[tid] = sw / se;
    }
    __syncthreads();

    // theoretical ions (38-element serial scans; negligible)
    if (tid == 0) {
      float c = 0.0f;
#pragma unroll
      for (int j = 0; j < 37; j++) {
        c += s_exp[1 + j];
        s_theo[j] = c + PROTON;             // b ions
        s_theo[74 + j] = c + PROTON - CO;   // a ions
      }
      float c2 = 0.0f;
#pragma unroll
      for (int j = 37; j >= 0; j--) {
        c2 += s_exp[1 + j];
        if (j <= 36) s_theo[37 + j] = c2 + WATER + PROTON;  // y ions
      }
    }
    __syncthreads();

    float contrib = 0.0f, cnt = 0.0f;
    if (tid < NION) {
      const float th = s_theo[tid];
      // binary search: first index with mass > th - 0.5
      const float lim = th - 0.5f;
      int lo = 0, hi = NPK;
      while (lo < hi) {
        int mid = (lo + hi) >> 1;
        if (s_mass[mid] <= lim) lo = mid + 1; else hi = mid;
      }
      // walk the tiny window; scores in [-5,0] so direct exp is exact-stable
      float se = 0.0f, sh = 0.0f, si = 0.0f;
      int has = 0;
      for (int p = lo; p < NPK; ++p) {
        float ms = s_mass[p];
        if (!(ms < th + 0.5f)) break;
        float iv = s_int[p];
        if (iv < 0.0f) continue;  // masked peak
        float d = fabsf(th - ms);
        if (!(d < 0.5f)) continue;
        float e = __expf(-10.0f * d);
        float hub = (d <= 0.2f) ? (0.5f * d * d) : (0.2f * (d - 0.1f));
        se += e; sh += e * hub; si += e * iv;
        has = 1;
      }
      if (has) {
        contrib = (sh / se) * (si / se);
        cnt = 1.0f;
      }
    }
    float s1 = blockReduceSum(contrib, red);
    __syncthreads();
    float s2 = blockReduceSum(cnt, red);
    if (tid == 0) {
      partial[2 * blockIdx.x] = s1;
      partial[2 * blockIdx.x + 1] = s2;
    }
  }
}

// ---------------- final reduce + combine ----------------
__global__ void __launch_bounds__(256) k_final(const float* __restrict__ partial,
                                               float* __restrict__ out) {
  __shared__ float red[8];
  float a0 = 0.0f, a1 = 0.0f, a2 = 0.0f, a3 = 0.0f;
  for (int i = threadIdx.x; i < NB_CE; i += 256) {
    a0 += partial[2 * i];
    a1 += partial[2 * i + 1];
  }
  for (int i = NB_CE + threadIdx.x; i < NBLK; i += 256) {
    a2 += partial[2 * i];
    a3 += partial[2 * i + 1];
  }
  a0 = blockReduceSum(a0, red); __syncthreads();
  a1 = blockReduceSum(a1, red); __syncthreads();
  a2 = blockReduceSum(a2, red); __syncthreads();
  a3 = blockReduceSum(a3, red);
  if (threadIdx.x == 0) {
    float ce = a0 / fmaxf(a1, 1.0f);
    float spec = a2 / fmaxf(a3, 1.0f);
    out[0] = ce + 0.1f * spec;
  }
}

extern "C" void kernel_launch(void* const* d_in, const int* in_sizes, int n_in,
                              void* d_out, int out_size, void* d_ws, size_t ws_size,
                              hipStream_t stream) {
  const float* all_logits = (const float*)d_in[0];
  const int* targets = (const int*)d_in[1];
  const uint8_t* target_mask = (const uint8_t*)d_in[2];
  const float* obs_m = (const float*)d_in[3];
  const float* obs_i = (const float*)d_in[4];
  const uint8_t* peak_mask = (const uint8_t*)d_in[5];
  const float* aa = (const float*)d_in[6];
  float* out = (float*)d_out;

  float* partial = (float*)d_ws;  // NBLK*2 floats, fully overwritten each call

  k_fused<<<NBLK, 256, 0, stream>>>(all_logits, targets, target_mask,
                                    obs_m, obs_i, peak_mask, aa, partial);
  k_final<<<1, 256, 0, stream>>>(partial, out);
}